// Round 23
// baseline (117.926 us; speedup 1.0000x reference)
//
#include <hip/hip_runtime.h>
#include <hip/hip_bf16.h>

typedef __attribute__((ext_vector_type(8))) __bf16 bf16x8;
typedef __attribute__((ext_vector_type(4))) float f32x4;
typedef __attribute__((ext_vector_type(4))) unsigned int u32x4;
typedef unsigned long long ull;

#define NB 16
#define CIN 32
#define COUT 64
#define HW 224
#define HP 226                  // padded spatial
#define HWHW (HW * HW)          // 50176
#define CHW (CIN * HW * HW)     // 1605632
#define WROW 296                // padded LDS row pitch in shorts
#define WS_X_OFF 65536          // bytes: wT at 0, padded NHWC X after

__device__ __forceinline__ unsigned short f2bf(float f) {
    __hip_bfloat16 h = __float2bfloat16(f);
    return __builtin_bit_cast(unsigned short, h);
}

// ---- K1: weight OIHW fp32 -> wT[co][tap][cin] bf16 (64*9*32 = 18432) ----
__global__ void k_wxform(const float* __restrict__ w, unsigned short* __restrict__ wT) {
    int i = blockIdx.x * 256 + threadIdx.x;
    if (i >= COUT * 9 * CIN) return;
    int co = i / (9 * CIN);
    int r  = i % (9 * CIN);
    int tap = r / CIN;
    int c   = r % CIN;
    wT[i] = f2bf(w[(co * CIN + c) * 9 + tap]);
}

// ---- K2: x NCHW fp32 -> X padded NHWC bf16 [16][226][226][32] (r4,
// correctness-verified). lane = pixel; per-lane contiguous channel vec. ----
__global__ __launch_bounds__(256)
void k_xform(const float* __restrict__ x, unsigned short* __restrict__ X) {
    int bid = blockIdx.x;                     // 16*226
    int b = bid / HP, hp = bid % HP;
    ull rowbase = (ull)(b * HP + hp) * (HP * CIN);
    u32x4 z = (u32x4){0u, 0u, 0u, 0u};
    if (hp >= 1 && hp <= HW) {
        int h = hp - 1;
        int wc = threadIdx.x;                 // 0..255
        if (wc < HW) {
            const float* xb = x + (ull)b * CHW + (ull)h * HW + wc;
            unsigned int packed[16];
            #pragma unroll
            for (int c2 = 0; c2 < 16; ++c2) {
                float f0 = __builtin_nontemporal_load(xb + (ull)(2 * c2) * HWHW);
                float f1 = __builtin_nontemporal_load(xb + (ull)(2 * c2 + 1) * HWHW);
                packed[c2] = (unsigned int)f2bf(f0) | ((unsigned int)f2bf(f1) << 16);
            }
            unsigned short* dst = X + rowbase + (ull)(1 + wc) * CIN;
            #pragma unroll
            for (int k = 0; k < 4; ++k) {     // normal stores: keep X in L2
                u32x4 v = (u32x4){packed[4 * k], packed[4 * k + 1],
                                  packed[4 * k + 2], packed[4 * k + 3]};
                *reinterpret_cast<u32x4*>(dst + k * 8) = v;
            }
        } else {
            int t = wc - HW;                  // idle lanes: w-pad columns
            if (t < 8) {
                ull off = (t < 4) ? (ull)t * 8 : (ull)(HP - 1) * CIN + (ull)(t - 4) * 8;
                *reinterpret_cast<u32x4*>(X + rowbase + off) = z;
            }
        }
    } else {                                  // top/bottom pad rows
        for (int i = threadIdx.x; i < (HP * CIN) / 8; i += 256)
            *reinterpret_cast<u32x4*>(X + rowbase + (ull)i * 8) = z;
    }
}

// ---- K3: lean conv from padded NHWC bf16. 4 waves x 64px x 64cout.
// No packing / masks / bpermute -> natural footprint ~50 VGPR + 64 AGPR
// fits (256,4)'s 128-reg combined budget: the occupancy the fused family
// could never reach (r8/r12/r15/r17/r21 all VGPR-squeezed). wT in LDS
// (r16 +14% win); xf = dense 16B loads (64 lanes = 1KB contiguous);
// nt stores for out. LDS 37.9KB x 4 blocks/CU = 151.6 <= 160KB. ----
__global__ __launch_bounds__(256, 4)
void k_conv(const unsigned short* __restrict__ X, const unsigned short* __restrict__ wT,
            const float* __restrict__ bias, float* __restrict__ out) {
    __shared__ __align__(16) unsigned short wlds[COUT * WROW];   // 37888 B

    int bid = blockIdx.x;
    int wg  = (bid & 7) * 448 + (bid >> 3);   // XCD-chunked swizzle, 3584 = 8*448
    int b = wg / HW, h = wg % HW;
    int tid = threadIdx.x;

    // stage wT -> LDS (row remap 288 -> 296 shorts), once per block
    {
        const u32x4* src = reinterpret_cast<const u32x4*>(wT);
        u32x4* dst = reinterpret_cast<u32x4*>(wlds);
        #pragma unroll
        for (int k = 0; k < 9; ++k) {              // 2304 = 9 * 256
            int i = k * 256 + tid;
            int co = i / 36, t = i % 36;
            dst[co * 37 + t] = src[i];
        }
    }
    __syncthreads();

    int wave = tid >> 6, lane = tid & 63;
    int r = lane & 15;                // px-local / cout-local row idx
    int q = lane >> 4;
    int chunk = q * 8;                // cin sub-chunk

    // clamped center px per frag (masked tail frags clamp in-bounds;
    // padding makes every (px+dw) slot 0..225 a valid X address)
    int pc[4];
    #pragma unroll
    for (int pf = 0; pf < 4; ++pf) {
        int cpx = wave * 64 + pf * 16 + r;
        pc[pf] = (cpx < HW) ? cpx : HW - 1;
    }
    const unsigned short* Xb = X + ((ull)b * HP + h) * (HP * CIN);  // row h+dh = padded h-1+dh+1

    f32x4 acc[4][4];
    #pragma unroll
    for (int i = 0; i < 4; ++i)
        #pragma unroll
        for (int j = 0; j < 4; ++j) acc[i][j] = (f32x4){0.f, 0.f, 0.f, 0.f};

    #pragma unroll
    for (int dh = 0; dh < 3; ++dh) {
        const unsigned short* Xrow = Xb + (ull)dh * (HP * CIN) + chunk;
        #pragma unroll
        for (int dw = 0; dw < 3; ++dw) {
            int tap = dh * 3 + dw;
            bf16x8 wf[4];
            #pragma unroll
            for (int cf = 0; cf < 4; ++cf)
                wf[cf] = *reinterpret_cast<const bf16x8*>(
                    wlds + (cf * 16 + r) * WROW + tap * 32 + chunk);
            bf16x8 xf[4];
            #pragma unroll
            for (int pf = 0; pf < 4; ++pf)
                xf[pf] = *reinterpret_cast<const bf16x8*>(Xrow + (ull)(pc[pf] + dw) * CIN);
            #pragma unroll
            for (int cf = 0; cf < 4; ++cf)
                #pragma unroll
                for (int pf = 0; pf < 4; ++pf)
                    acc[cf][pf] = __builtin_amdgcn_mfma_f32_16x16x32_bf16(
                        xf[pf], wf[cf], acc[cf][pf], 0, 0, 0);
        }
    }

    // epilogue: D row = px = q*4+reg, col = cout = r; nt f32x4 stores
    #pragma unroll
    for (int cf = 0; cf < 4; ++cf) {
        int co = cf * 16 + r;
        float bv = bias[co];
        float* orow = out + ((ull)(b * COUT + co) * HW + h) * HW;
        #pragma unroll
        for (int pf = 0; pf < 4; ++pf) {
            int pxb = wave * 64 + pf * 16;
            if (pxb < HW) {                  // frag fully valid or fully masked
                int px0 = pxb + q * 4;
                f32x4 v = acc[cf][pf] + bv;
                __builtin_nontemporal_store(v, reinterpret_cast<f32x4*>(orow + px0));
            }
        }
    }
}

// ---- fallback: naive direct fp32 conv (used only if ws too small) ----
__global__ void k_naive(const float* __restrict__ x, const float* __restrict__ w,
                        const float* __restrict__ bias, float* __restrict__ out, long long n) {
    long long i = (long long)blockIdx.x * 256 + threadIdx.x;
    if (i >= n) return;
    int wc = i % HW; long long t = i / HW;
    int h = t % HW; t /= HW;
    int co = t % COUT; int b = (int)(t / COUT);
    float s = bias[co];
    for (int c = 0; c < CIN; ++c)
        for (int dh = 0; dh < 3; ++dh) {
            int hy = h + dh - 1; if (hy < 0 || hy >= HW) continue;
            for (int dw = 0; dw < 3; ++dw) {
                int wx = wc + dw - 1; if (wx < 0 || wx >= HW) continue;
                s += x[(((long long)b * CIN + c) * HW + hy) * HW + wx] *
                     w[((co * CIN + c) * 3 + dh) * 3 + dw];
            }
        }
    out[i] = s;
}

extern "C" void kernel_launch(void* const* d_in, const int* in_sizes, int n_in,
                              void* d_out, int out_size, void* d_ws, size_t ws_size,
                              hipStream_t stream) {
    const float* x    = (const float*)d_in[0];
    const float* w    = (const float*)d_in[1];
    const float* bias = (const float*)d_in[2];
    float* out = (float*)d_out;

    size_t need = (size_t)WS_X_OFF + (size_t)NB * HP * HP * CIN * 2 + 4096;
    if (ws_size < need) {
        long long n = (long long)NB * COUT * HW * HW;
        k_naive<<<(int)((n + 255) / 256), 256, 0, stream>>>(x, w, bias, out, n);
        return;
    }
    unsigned short* wT = (unsigned short*)d_ws;
    unsigned short* X  = (unsigned short*)((char*)d_ws + WS_X_OFF);

    k_wxform<<<72, 256, 0, stream>>>(w, wT);
    k_xform<<<NB * HP, 256, 0, stream>>>(x, X);
    k_conv<<<NB * HW, 256, 0, stream>>>(X, wT, bias, out);
}

// Round 24
// 83.257 us; speedup vs baseline: 1.4164x; 1.4164x over previous
//
#include <hip/hip_runtime.h>
#include <hip/hip_bf16.h>

typedef __attribute__((ext_vector_type(8))) __bf16 bf16x8;
typedef __attribute__((ext_vector_type(4))) float f32x4;
typedef __attribute__((ext_vector_type(4))) unsigned int u32x4;
typedef unsigned long long ull;

#define NB 16
#define CIN 32
#define COUT 64
#define HW 224
#define HWHW (HW * HW)          // 50176
#define CHW (CIN * HW * HW)     // 1605632
#define WROW 296                // padded LDS row pitch in shorts (148 dwords)

__device__ __forceinline__ unsigned short f2bf(float f) {
    __hip_bfloat16 h = __float2bfloat16(f);
    return __builtin_bit_cast(unsigned short, h);
}

// ---- K1: weight OIHW fp32 -> wT[co][tap][cin] bf16 (64*9*32 = 18432) ----
__global__ void k_wxform(const float* __restrict__ w, unsigned short* __restrict__ wT) {
    int i = blockIdx.x * 256 + threadIdx.x;
    if (i >= COUT * 9 * CIN) return;
    int co = i / (9 * CIN);
    int r  = i % (9 * CIN);
    int tap = r / CIN;
    int c   = r % CIN;
    wT[i] = f2bf(w[(co * CIN + c) * 9 + tap]);
}

// ---- K2: fused conv — FINAL (session optimum, 83.3us, reproduced twice).
// 4 waves x 64px x 64cout, one block per (b,h). Register gather of NCHW
// fp32 (wide per-dh bursts), bf16 pack in-register, bpermute shift-dedup
// for dw=+/-1 (cuts VMEM 3x), wT staged in LDS (36KB table overflows L1;
// staging it was +14%), nt f32x4 stores (A/B tested faster than normal
// despite +75MB WRITE), XCD-chunked blockIdx swizzle.
// Design space exhausted both directions: acc=64 @ 3 waves/SIMD full-reg
// is optimal — every higher-occupancy config (r8/r12/r13/r15/r17/r21)
// was VGPR-squeezed or spilled by the unified VGPR+AGPR file; every
// source-level software pipeline (r18/r19/r20) was spilled or sunk by
// the allocator; two-phase NHWC pre-materialization (r23: 117.9us) costs
// more round-trip traffic than the latency it buys. Remaining gap to the
// 52us HBM floor is unhidden gather latency at 9 waves/CU. ----
__global__ __launch_bounds__(256, 3)
void k_fused(const float* __restrict__ x, const unsigned short* __restrict__ wT,
             const float* __restrict__ bias, float* __restrict__ out) {
    __shared__ __align__(16) unsigned short wlds[COUT * WROW];   // 37888 B

    int bid = blockIdx.x;
    int wg  = (bid & 7) * 448 + (bid >> 3);   // XCD-chunked swizzle, 3584 = 8*448
    int b = wg / HW, h = wg % HW;
    int tid = threadIdx.x;

    // stage wT -> LDS (row remap 288 -> 296 shorts), once per block
    {
        const u32x4* src = reinterpret_cast<const u32x4*>(wT);
        u32x4* dst = reinterpret_cast<u32x4*>(wlds);
        #pragma unroll
        for (int k = 0; k < 9; ++k) {              // 2304 = 9 * 256
            int i = k * 256 + tid;
            int co = i / 36, t = i % 36;
            dst[co * 37 + t] = src[i];
        }
    }
    __syncthreads();

    int wave = tid >> 6, lane = tid & 63;
    int r = lane & 15;                // px-local / cout-local row idx
    int q = lane >> 4;
    int chunk = q * 8;                // cin sub-chunk
    const float* xb = x + (ull)b * CHW + (ull)chunk * HWHW;

    // byte-index regs for ds_bpermute rotations within each 16-lane group
    int idxm = (((lane & 48) | ((lane - 1) & 15)) << 2);   // pull from r-1 (wrap)
    int idxp = (((lane & 48) | ((lane + 1) & 15)) << 2);   // pull from r+1 (wrap)
    bool r0  = (r == 0), r15 = (r == 15);

    // dh-independent center/halo pixel coords + validity (clamped, branch-free)
    int pc[4];
    unsigned int cm[4];
    #pragma unroll
    for (int pf = 0; pf < 4; ++pf) {
        int cpx = wave * 64 + pf * 16 + r;
        cm[pf] = (cpx < HW) ? 0xFFFFFFFFu : 0u;
        pc[pf] = (cpx < HW) ? cpx : HW - 1;
    }
    int hlp = wave * 64 - 1;
    unsigned int lm = (hlp >= 0) ? 0xFFFFFFFFu : 0u;
    hlp = (hlp >= 0) ? hlp : 0;
    int hrp = wave * 64 + 64;
    unsigned int rm = (hrp < HW) ? 0xFFFFFFFFu : 0u;
    hrp = (hrp < HW) ? hrp : HW - 1;

    f32x4 acc[4][4];
    #pragma unroll
    for (int i = 0; i < 4; ++i)
        #pragma unroll
        for (int j = 0; j < 4; ++j) acc[i][j] = (f32x4){0.f, 0.f, 0.f, 0.f};

    #pragma unroll
    for (int dh = 0; dh < 3; ++dh) {
        int hy = h + dh - 1;
        unsigned int rowm = ((unsigned)hy < (unsigned)HW) ? 0xFFFFFFFFu : 0u;
        int hyc = hy < 0 ? 0 : (hy > HW - 1 ? HW - 1 : hy);
        const float* xrow = xb + (ull)hyc * HW;

        // ---- phase A: issue ALL 48 loads of this dh before any use ----
        float raw[48];
        #pragma unroll
        for (int pf = 0; pf < 4; ++pf) {
            const float* p = xrow + pc[pf];
            #pragma unroll
            for (int j = 0; j < 8; ++j)
                raw[pf * 8 + j] = p[(ull)j * HWHW];
        }
        {
            const float* p = xrow + hlp;
            #pragma unroll
            for (int j = 0; j < 8; ++j) raw[32 + j] = p[(ull)j * HWHW];
        }
        {
            const float* p = xrow + hrp;
            #pragma unroll
            for (int j = 0; j < 8; ++j) raw[40 + j] = p[(ull)j * HWHW];
        }
        __builtin_amdgcn_sched_barrier(0);   // keep all loads above the packs

        // ---- phase B: pack to bf16 pairs + masks ----
        unsigned int own[4][4], hl[4], hr[4];
        #pragma unroll
        for (int pf = 0; pf < 4; ++pf) {
            unsigned int zm = cm[pf] & rowm;
            #pragma unroll
            for (int j = 0; j < 4; ++j)
                own[pf][j] = ((unsigned)f2bf(raw[pf * 8 + 2 * j]) |
                              ((unsigned)f2bf(raw[pf * 8 + 2 * j + 1]) << 16)) & zm;
        }
        {
            unsigned int zm = lm & rowm;
            #pragma unroll
            for (int j = 0; j < 4; ++j)
                hl[j] = ((unsigned)f2bf(raw[32 + 2 * j]) |
                         ((unsigned)f2bf(raw[32 + 2 * j + 1]) << 16)) & zm;
        }
        {
            unsigned int zm = rm & rowm;
            #pragma unroll
            for (int j = 0; j < 4; ++j)
                hr[j] = ((unsigned)f2bf(raw[40 + 2 * j]) |
                         ((unsigned)f2bf(raw[40 + 2 * j + 1]) << 16)) & zm;
        }

        // ---- phase W: hoist this dh's 12 wf fragments from LDS ----
        bf16x8 wfd[3][4];
        #pragma unroll
        for (int dw = 0; dw < 3; ++dw)
            #pragma unroll
            for (int cf = 0; cf < 4; ++cf)
                wfd[dw][cf] = *reinterpret_cast<const bf16x8*>(
                    wlds + (cf * 16 + r) * WROW + (dh * 3 + dw) * 32 + chunk);

        // ---- phase C: shifts via bpermute + MFMA ----
        #pragma unroll
        for (int dw = 0; dw < 3; ++dw) {
            bf16x8 xf[4];
            #pragma unroll
            for (int pf = 0; pf < 4; ++pf) {
                u32x4 t;
                if (dw == 1) {
                    t = (u32x4){own[pf][0], own[pf][1], own[pf][2], own[pf][3]};
                } else if (dw == 0) {        // col px-1: pull from r-1
                    #pragma unroll
                    for (int j = 0; j < 4; ++j) {
                        int A = __builtin_amdgcn_ds_bpermute(idxm, (int)own[pf][j]);
                        int B = (pf > 0)
                            ? __builtin_amdgcn_ds_bpermute(idxm, (int)own[pf - 1][j])
                            : (int)hl[j];
                        t[j] = (unsigned int)(r0 ? B : A);
                    }
                } else {                      // col px+1: pull from r+1
                    #pragma unroll
                    for (int j = 0; j < 4; ++j) {
                        int A = __builtin_amdgcn_ds_bpermute(idxp, (int)own[pf][j]);
                        int B = (pf < 3)
                            ? __builtin_amdgcn_ds_bpermute(idxp, (int)own[pf + 1][j])
                            : (int)hr[j];
                        t[j] = (unsigned int)(r15 ? B : A);
                    }
                }
                xf[pf] = __builtin_bit_cast(bf16x8, t);
            }
            #pragma unroll
            for (int cf = 0; cf < 4; ++cf)
                #pragma unroll
                for (int pf = 0; pf < 4; ++pf)
                    acc[cf][pf] = __builtin_amdgcn_mfma_f32_16x16x32_bf16(
                        xf[pf], wfd[dw][cf], acc[cf][pf], 0, 0, 0);
        }
    }

    // epilogue: D row = px = q*4+reg, col = cout = r; nt stores
    #pragma unroll
    for (int cf = 0; cf < 4; ++cf) {
        int co = cf * 16 + r;
        float bv = bias[co];
        float* orow = out + ((ull)(b * COUT + co) * HW + h) * HW;
        #pragma unroll
        for (int pf = 0; pf < 4; ++pf) {
            int pxb = wave * 64 + pf * 16;
            if (pxb < HW) {                  // frag fully valid or fully masked
                int px0 = pxb + q * 4;
                f32x4 v = acc[cf][pf] + bv;
                __builtin_nontemporal_store(v, reinterpret_cast<f32x4*>(orow + px0));
            }
        }
    }
}

// ---- fallback: naive direct fp32 conv (used only if ws too small) ----
__global__ void k_naive(const float* __restrict__ x, const float* __restrict__ w,
                        const float* __restrict__ bias, float* __restrict__ out, long long n) {
    long long i = (long long)blockIdx.x * 256 + threadIdx.x;
    if (i >= n) return;
    int wc = i % HW; long long t = i / HW;
    int h = t % HW; t /= HW;
    int co = t % COUT; int b = (int)(t / COUT);
    float s = bias[co];
    for (int c = 0; c < CIN; ++c)
        for (int dh = 0; dh < 3; ++dh) {
            int hy = h + dh - 1; if (hy < 0 || hy >= HW) continue;
            for (int dw = 0; dw < 3; ++dw) {
                int wx = wc + dw - 1; if (wx < 0 || wx >= HW) continue;
                s += x[(((long long)b * CIN + c) * HW + hy) * HW + wx] *
                     w[((co * CIN + c) * 3 + dh) * 3 + dw];
            }
        }
    out[i] = s;
}

extern "C" void kernel_launch(void* const* d_in, const int* in_sizes, int n_in,
                              void* d_out, int out_size, void* d_ws, size_t ws_size,
                              hipStream_t stream) {
    const float* x    = (const float*)d_in[0];
    const float* w    = (const float*)d_in[1];
    const float* bias = (const float*)d_in[2];
    float* out = (float*)d_out;

    if (ws_size < (size_t)(COUT * 9 * CIN * 2 + 1024)) {
        long long n = (long long)NB * COUT * HW * HW;
        k_naive<<<(int)((n + 255) / 256), 256, 0, stream>>>(x, w, bias, out, n);
        return;
    }
    unsigned short* wT = (unsigned short*)d_ws;

    k_wxform<<<72, 256, 0, stream>>>(w, wT);
    k_fused<<<NB * HW, 256, 0, stream>>>(x, wT, bias, out);
}